// Round 11
// baseline (224.414 us; speedup 1.0000x reference)
//
#include <hip/hip_runtime.h>
#include <hip/hip_bf16.h>
#include <hip/hip_fp16.h>

#define NN 100000      // nodes
#define NE 1000000     // edges
#define EPB 1024       // edges per block in edge passes
#define NBLK 977       // ceil(NE/EPB)
#define NBKT 391       // buckets: bucket = dst>>8 (256 nodes each) == consumer blocks
#define HSTR 392       // HT row stride in u32 (HT[block][bucket])
#define SCAP 6144      // LDS edge-buffer capacity per bucket (avg 2560, max ~2800)

// ---------------- workspace layout (4-byte units) ----------------
#define OFF_PFEAT    0              // float4[NN] {f0,f1,f2,el1}
#define OFF_ER1      400000         // f32[NN]
#define OFF_ER2      500000         // f32[NN]
#define OFF_TOT      600000         // u32[NBKT]
#define OFF_BBASE    600391         // u32[NBKT+1]  (published by kC block 0)
#define OFF_HT       600800         // u32[NBLK*HSTR]  HT[block][bucket]
#define OFF_PCK      983808         // u32[NE] bucket-partitioned packed {dstlocal:8|src:17}
#define OFF_Z2H      1983808        // half[32*NN] (64B rows; [30]=el2) 16B-aligned
#define OFF_ACC      3583808        // f32[32]  global column-sum accumulator (atomics)
#define OFF_CTR      3583840        // u32[1]   last-block ticket counter

#define PK2(a,b) __builtin_bit_cast(float, __floats2half2_rn((a),(b)))

// pass A: per-block LDS histogram over 391 buckets; coalesced HT row write.
// Each block computes cl/cr itself; low blocks pack pfeat/er1.
__global__ void kA_hist(const int* __restrict__ dst, const float* __restrict__ feat,
                        const float* __restrict__ W1, const float* __restrict__ al1,
                        const float* __restrict__ ar1, unsigned* __restrict__ HT,
                        float4* __restrict__ pfeat, float* __restrict__ er1) {
    __shared__ unsigned h[NBKT];
    __shared__ float scl[3], scr[3];
    int tid = threadIdx.x;
    if (tid < 64) {
        float a = al1[tid], r = ar1[tid];
#pragma unroll
        for (int k = 0; k < 3; ++k) {
            float wv = W1[k*128 + tid];
            float vl = wv * a, vr = wv * r;
            for (int off = 32; off > 0; off >>= 1) {
                vl += __shfl_down(vl, off);
                vr += __shfl_down(vr, off);
            }
            if (tid == 0) { scl[k] = vl; scr[k] = vr; }
        }
    }
    for (int i = tid; i < NBKT; i += 256) h[i] = 0u;
    __syncthreads();
    int e0 = blockIdx.x * EPB + tid * 4;
    if (e0 + 4 <= NE) {
        int4 d4 = *(const int4*)(dst + e0);
        atomicAdd(&h[d4.x >> 8], 1u);
        atomicAdd(&h[d4.y >> 8], 1u);
        atomicAdd(&h[d4.z >> 8], 1u);
        atomicAdd(&h[d4.w >> 8], 1u);
    } else {
        for (int e = e0; e < NE; ++e) atomicAdd(&h[dst[e] >> 8], 1u);
    }
    int n = blockIdx.x * 256 + tid;
    if (n < NN) {
        float f0 = feat[n*3], f1 = feat[n*3+1], f2 = feat[n*3+2];
        pfeat[n] = make_float4(f0, f1, f2, f0*scl[0] + f1*scl[1] + f2*scl[2]);
        er1[n] = f0*scr[0] + f1*scr[1] + f2*scr[2];
    }
    __syncthreads();
    unsigned* row = HT + (size_t)blockIdx.x * HSTR;
    for (int k = tid; k < NBKT; k += 256) row[k] = h[k];
}

// pass B: one block per bucket: exclusive scan over blocks of HT[b][bucket] + total.
// Block 0 also zeroes the global accumulator + ticket counter for kG2's epilogue.
__global__ void kB_scan(unsigned* __restrict__ HT, unsigned* __restrict__ tot,
                        float* __restrict__ acc, unsigned* __restrict__ ctr) {
    __shared__ unsigned sh[256];
    int t = threadIdx.x;
    int kb = blockIdx.x;
    if (kb == 0 && t < 32) {
        if (t < 30) acc[t] = 0.f;
        if (t == 31) ctr[0] = 0u;
    }
    unsigned v[4], ex[4];
    unsigned s = 0;
#pragma unroll
    for (int j = 0; j < 4; ++j) {
        int b = t*4 + j;
        v[j] = (b < NBLK) ? HT[(size_t)b * HSTR + kb] : 0u;
        ex[j] = s;
        s += v[j];
    }
    sh[t] = s;
    __syncthreads();
    for (int off = 1; off < 256; off <<= 1) {
        unsigned u = (t >= off) ? sh[t - off] : 0u;
        __syncthreads();
        sh[t] += u;
        __syncthreads();
    }
    unsigned base = sh[t] - s;
#pragma unroll
    for (int j = 0; j < 4; ++j) {
        int b = t*4 + j;
        if (b < NBLK) HT[(size_t)b * HSTR + kb] = base + ex[j];
    }
    if (t == 255) tot[kb] = sh[255];
}

// pass C: rank edges per (block,bucket) via LDS atomics, LDS-sort by bucket,
// write bucket-sorted runs. Computes bbase in-LDS from tot; block 0 publishes it.
__global__ void kC_scatter(const int* __restrict__ src, const int* __restrict__ dst,
                           const unsigned* __restrict__ HT, const unsigned* __restrict__ tot,
                           unsigned* __restrict__ bbase, unsigned* __restrict__ pck) {
    __shared__ unsigned sCnt[NBKT];
    __shared__ unsigned sPos[NBKT];
    __shared__ unsigned sBB[NBKT];
    __shared__ unsigned sDelta[NBKT];
    __shared__ unsigned sBuf[EPB];
    __shared__ unsigned short sBkt[EPB];
    __shared__ unsigned sh[256];
    int tid = threadIdx.x;
    for (int k = tid; k < NBKT; k += 256) sCnt[k] = 0u;
    __syncthreads();
    int vcnt = NE - blockIdx.x * EPB;
    if (vcnt > EPB) vcnt = EPB;
    int e0 = blockIdx.x * EPB + tid * 4;
    int nv = vcnt - tid * 4;
    unsigned w0=0,w1=0,w2=0,w3=0, b0=0,b1=0,b2=0,b3=0, r0=0,r1=0,r2=0,r3=0;
    if (nv >= 4) {
        int4 s4 = *(const int4*)(src + e0);
        int4 d4 = *(const int4*)(dst + e0);
        b0 = (unsigned)d4.x >> 8; r0 = atomicAdd(&sCnt[b0], 1u);
        w0 = (unsigned)s4.x | (((unsigned)d4.x & 255u) << 17);
        b1 = (unsigned)d4.y >> 8; r1 = atomicAdd(&sCnt[b1], 1u);
        w1 = (unsigned)s4.y | (((unsigned)d4.y & 255u) << 17);
        b2 = (unsigned)d4.z >> 8; r2 = atomicAdd(&sCnt[b2], 1u);
        w2 = (unsigned)s4.z | (((unsigned)d4.z & 255u) << 17);
        b3 = (unsigned)d4.w >> 8; r3 = atomicAdd(&sCnt[b3], 1u);
        w3 = (unsigned)s4.w | (((unsigned)d4.w & 255u) << 17);
    } else if (nv > 0) {
        if (nv >= 1) { unsigned d = (unsigned)dst[e0];   b0 = d >> 8; r0 = atomicAdd(&sCnt[b0], 1u); w0 = (unsigned)src[e0]   | ((d & 255u) << 17); }
        if (nv >= 2) { unsigned d = (unsigned)dst[e0+1]; b1 = d >> 8; r1 = atomicAdd(&sCnt[b1], 1u); w1 = (unsigned)src[e0+1] | ((d & 255u) << 17); }
        if (nv >= 3) { unsigned d = (unsigned)dst[e0+2]; b2 = d >> 8; r2 = atomicAdd(&sCnt[b2], 1u); w2 = (unsigned)src[e0+2] | ((d & 255u) << 17); }
    }
    __syncthreads();
    // scan 1: sCnt -> sPos (exclusive within block)
    unsigned c0 = (2*tid     < NBKT) ? sCnt[2*tid]     : 0u;
    unsigned c1 = (2*tid + 1 < NBKT) ? sCnt[2*tid + 1] : 0u;
    unsigned ssum = c0 + c1;
    sh[tid] = ssum;
    __syncthreads();
    for (int off = 1; off < 256; off <<= 1) {
        unsigned u = (tid >= off) ? sh[tid - off] : 0u;
        __syncthreads();
        sh[tid] += u;
        __syncthreads();
    }
    unsigned base = sh[tid] - ssum;
    if (2*tid     < NBKT) sPos[2*tid]     = base;
    if (2*tid + 1 < NBKT) sPos[2*tid + 1] = base + c0;
    __syncthreads();
    if (nv >= 4) {
        unsigned i;
        i = sPos[b0] + r0; sBuf[i] = w0; sBkt[i] = (unsigned short)b0;
        i = sPos[b1] + r1; sBuf[i] = w1; sBkt[i] = (unsigned short)b1;
        i = sPos[b2] + r2; sBuf[i] = w2; sBkt[i] = (unsigned short)b2;
        i = sPos[b3] + r3; sBuf[i] = w3; sBkt[i] = (unsigned short)b3;
    } else if (nv > 0) {
        unsigned i;
        if (nv >= 1) { i = sPos[b0] + r0; sBuf[i] = w0; sBkt[i] = (unsigned short)b0; }
        if (nv >= 2) { i = sPos[b1] + r1; sBuf[i] = w1; sBkt[i] = (unsigned short)b1; }
        if (nv >= 3) { i = sPos[b2] + r2; sBuf[i] = w2; sBkt[i] = (unsigned short)b2; }
    }
    // scan 2: tot -> sBB (bucket bases)
    unsigned t0 = (2*tid     < NBKT) ? tot[2*tid]     : 0u;
    unsigned t1 = (2*tid + 1 < NBKT) ? tot[2*tid + 1] : 0u;
    unsigned ss2 = t0 + t1;
    sh[tid] = ss2;
    __syncthreads();
    for (int off = 1; off < 256; off <<= 1) {
        unsigned u = (tid >= off) ? sh[tid - off] : 0u;
        __syncthreads();
        sh[tid] += u;
        __syncthreads();
    }
    unsigned b2x = sh[tid] - ss2;
    if (2*tid     < NBKT) sBB[2*tid]     = b2x;
    if (2*tid + 1 < NBKT) sBB[2*tid + 1] = b2x + t0;
    __syncthreads();
    if (blockIdx.x == 0) {
        for (int k = tid; k < NBKT; k += 256) bbase[k] = sBB[k];
        if (tid == 0) bbase[NBKT] = NE;
    }
    {
        const unsigned* row = HT + (size_t)blockIdx.x * HSTR;
        for (int k = tid; k < NBKT; k += 256)
            sDelta[k] = sBB[k] + row[k] - sPos[k];
    }
    __syncthreads();
    for (int i = tid; i < vcnt; i += 256)
        pck[i + sDelta[sBkt[i]]] = sBuf[i];
}

// kG1: 512 threads per bucket. LDS sort (stride-512 phases), then 2 threads per
// node consume interleaved edge halves; partials merged via LDS; per-node MLP ->
// z2 row (fp16) + er2 on threads <256.
__global__ void kG1_node(const unsigned* __restrict__ bbase, const unsigned* __restrict__ pck,
                         const float4* __restrict__ pfeat, const float* __restrict__ er1,
                         const float* __restrict__ W1, const float* __restrict__ b1,
                         const float* __restrict__ W2, const float* __restrict__ al2,
                         const float* __restrict__ ar2,
                         __half* __restrict__ z2h, float* __restrict__ er2) {
    __shared__ float sW1[192], sb1[64], sW2[1920], sal2[30], sar2[30];
    __shared__ unsigned h[256], pr[256], cur[256];
    __shared__ unsigned sBuf[SCAP];
    __shared__ float xch[4][256];
    int tid = threadIdx.x;
    for (int i = tid; i < 192; i += 512) sW1[i] = W1[(i >> 6)*128 + (i & 63)];
    for (int i = tid; i < 1920; i += 512) sW2[i] = W2[(i / 30)*60 + (i % 30)];
    if (tid < 64) sb1[tid] = b1[tid];
    if (tid < 30) { sal2[tid] = al2[tid]; sar2[tid] = ar2[tid]; }
    unsigned bb = bbase[blockIdx.x], be = bbase[blockIdx.x + 1];
    unsigned cnt = be - bb;
    bool fit = (cnt <= SCAP);               // block-uniform
    if (tid < 256) { h[tid] = 0u; cur[tid] = 0u; }
    __syncthreads();
    if (fit) {
        for (unsigned i = bb + tid; i < be; i += 512) atomicAdd(&h[pck[i] >> 17], 1u);
        __syncthreads();
        unsigned v = 0;
        if (tid < 256) { v = h[tid]; pr[tid] = v; }
        __syncthreads();
        for (int off = 1; off < 256; off <<= 1) {
            unsigned u = 0;
            if (tid < 256 && tid >= off) u = pr[tid - off];
            __syncthreads();
            if (tid < 256) pr[tid] += u;
            __syncthreads();
        }
        if (tid < 256) pr[tid] -= v;
        __syncthreads();
        for (unsigned i = bb + tid; i < be; i += 512) {
            unsigned w = pck[i];
            unsigned j = w >> 17;
            unsigned r = atomicAdd(&cur[j], 1u);
            sBuf[pr[j] + r] = w & 0x1FFFFu;
        }
        __syncthreads();
    }
    int j = tid & 255, half = tid >> 8;
    int n = blockIdx.x * 256 + j;
    bool valid = (n < NN);
    float s0 = 0.f, s1 = 0.f, s2 = 0.f, sp = 0.f;
    if (valid) {
        float erd = er1[n];
        if (fit) {
            unsigned beg = pr[j], end = beg + h[j];
            unsigned i = beg + half;                 // this half's edges: stride 2
            for (; i + 2 < end; i += 4) {            // 2 gathers in flight
                unsigned sA = sBuf[i], sB = sBuf[i + 2];
                float4 vA = pfeat[sA], vB = pfeat[sB];
                float eA = vA.w + erd; eA = (eA >= 0.f) ? eA : 0.2f*eA; float pA = __expf(eA);
                s0 += pA*vA.x; s1 += pA*vA.y; s2 += pA*vA.z; sp += pA;
                float eB = vB.w + erd; eB = (eB >= 0.f) ? eB : 0.2f*eB; float pB = __expf(eB);
                s0 += pB*vB.x; s1 += pB*vB.y; s2 += pB*vB.z; sp += pB;
            }
            if (i < end) {
                unsigned s = sBuf[i];
                float4 v = pfeat[s];
                float ee = v.w + erd; ee = (ee >= 0.f) ? ee : 0.2f*ee; float p = __expf(ee);
                s0 += p*v.x; s1 += p*v.y; s2 += p*v.z; sp += p;
            }
        } else if (half == 0) {                      // exact fallback (never here)
            for (unsigned i = bb; i < be; ++i) {
                unsigned w = pck[i];
                if ((int)(w >> 17) == j) {
                    float4 v = pfeat[w & 0x1FFFFu];
                    float ee = v.w + erd; ee = (ee >= 0.f) ? ee : 0.2f*ee; float p = __expf(ee);
                    s0 += p*v.x; s1 += p*v.y; s2 += p*v.z; sp += p;
                }
            }
        }
    }
    if (half == 1) { xch[0][j] = s0; xch[1][j] = s1; xch[2][j] = s2; xch[3][j] = sp; }
    __syncthreads();
    if (tid >= 256 || !valid) return;
    s0 += xch[0][tid]; s1 += xch[1][tid]; s2 += xch[2][tid]; sp += xch[3][tid];
    float inv = (sp > 0.f) ? 1.f / sp : 0.f;
    float ax = s0 * inv, ay = s1 * inv, az = s2 * inv;
    float z[30];
#pragma unroll
    for (int c = 0; c < 30; ++c) z[c] = 0.f;
    for (int jj = 0; jj < 64; ++jj) {
        float rj = fmaxf(ax*sW1[jj] + ay*sW1[64 + jj] + az*sW1[128 + jj] + sb1[jj], 0.f);
#pragma unroll
        for (int c = 0; c < 30; ++c) z[c] += rj * sW2[jj*30 + c];
    }
    float sl = 0.f, sr = 0.f;
#pragma unroll
    for (int c = 0; c < 30; ++c) { sl += z[c] * sal2[c]; sr += z[c] * sar2[c]; }
    float4* outp = (float4*)(z2h + (size_t)n * 32);
    outp[0] = make_float4(PK2(z[0],z[1]),  PK2(z[2],z[3]),  PK2(z[4],z[5]),  PK2(z[6],z[7]));
    outp[1] = make_float4(PK2(z[8],z[9]),  PK2(z[10],z[11]),PK2(z[12],z[13]),PK2(z[14],z[15]));
    outp[2] = make_float4(PK2(z[16],z[17]),PK2(z[18],z[19]),PK2(z[20],z[21]),PK2(z[22],z[23]));
    outp[3] = make_float4(PK2(z[24],z[25]),PK2(z[26],z[27]),PK2(z[28],z[29]),PK2(sl, 0.f));
    er2[n] = sr;
}

// kG2: 512 threads per bucket. LDS sort, 2 threads/node consume interleaved halves,
// block reduction -> device-scope atomicAdd into global acc; last block (ticket)
// runs the k6 epilogue in-place (acc read back via atomic path — cross-XCD safe).
__global__ void kG2_layer2(const unsigned* __restrict__ bbase, const unsigned* __restrict__ pck,
                           const __half* __restrict__ z2h, const float* __restrict__ er2,
                           float* __restrict__ acc_g, unsigned* __restrict__ ctr,
                           const float* __restrict__ x, const float* __restrict__ vocab,
                           const float* __restrict__ W_lin1, const float* __restrict__ w2c,
                           const float* __restrict__ w3c, const float* __restrict__ W4,
                           const float* __restrict__ b2v, float* __restrict__ out) {
    __shared__ unsigned h[256], pr[256], cur[256];
    __shared__ unsigned sBuf[SCAP];
    __shared__ float xsp[2][256];
    __shared__ float shr[8][32];
    __shared__ float sh6[256];
    __shared__ float hvec[70];
    __shared__ int isLast;
    int tid = threadIdx.x;
    int lane = tid & 63, wv = tid >> 6;   // 8 waves
    unsigned bb = bbase[blockIdx.x], be = bbase[blockIdx.x + 1];
    unsigned cnt = be - bb;
    bool fit = (cnt <= SCAP);
    if (tid < 256) { h[tid] = 0u; cur[tid] = 0u; }
    __syncthreads();
    if (fit) {
        for (unsigned i = bb + tid; i < be; i += 512) atomicAdd(&h[pck[i] >> 17], 1u);
        __syncthreads();
        unsigned v = 0;
        if (tid < 256) { v = h[tid]; pr[tid] = v; }
        __syncthreads();
        for (int off = 1; off < 256; off <<= 1) {
            unsigned u = 0;
            if (tid < 256 && tid >= off) u = pr[tid - off];
            __syncthreads();
            if (tid < 256) pr[tid] += u;
            __syncthreads();
        }
        if (tid < 256) pr[tid] -= v;
        __syncthreads();
        for (unsigned i = bb + tid; i < be; i += 512) {
            unsigned w = pck[i];
            unsigned j = w >> 17;
            unsigned r = atomicAdd(&cur[j], 1u);
            sBuf[pr[j] + r] = w & 0x1FFFFu;
        }
        __syncthreads();
    }
    int j = tid & 255, half = tid >> 8;
    int n = blockIdx.x * 256 + j;
    bool valid = (n < NN);
    float acc[30];
#pragma unroll
    for (int q = 0; q < 30; ++q) acc[q] = 0.f;
    float sp = 0.f;
    if (valid) {
        float erd = er2[n];
#define PROC(r0, r1, r2, r3) { \
            float el = __half2float(__low2half(__builtin_bit_cast(__half2, (r3).w))); \
            float ee = el + erd; \
            ee = (ee >= 0.f) ? ee : 0.2f * ee; \
            float p = __expf(ee); \
            sp += p; \
            float2 f; \
            f = __half22float2(__builtin_bit_cast(__half2, (r0).x)); acc[0]  += p*f.x; acc[1]  += p*f.y; \
            f = __half22float2(__builtin_bit_cast(__half2, (r0).y)); acc[2]  += p*f.x; acc[3]  += p*f.y; \
            f = __half22float2(__builtin_bit_cast(__half2, (r0).z)); acc[4]  += p*f.x; acc[5]  += p*f.y; \
            f = __half22float2(__builtin_bit_cast(__half2, (r0).w)); acc[6]  += p*f.x; acc[7]  += p*f.y; \
            f = __half22float2(__builtin_bit_cast(__half2, (r1).x)); acc[8]  += p*f.x; acc[9]  += p*f.y; \
            f = __half22float2(__builtin_bit_cast(__half2, (r1).y)); acc[10] += p*f.x; acc[11] += p*f.y; \
            f = __half22float2(__builtin_bit_cast(__half2, (r1).z)); acc[12] += p*f.x; acc[13] += p*f.y; \
            f = __half22float2(__builtin_bit_cast(__half2, (r1).w)); acc[14] += p*f.x; acc[15] += p*f.y; \
            f = __half22float2(__builtin_bit_cast(__half2, (r2).x)); acc[16] += p*f.x; acc[17] += p*f.y; \
            f = __half22float2(__builtin_bit_cast(__half2, (r2).y)); acc[18] += p*f.x; acc[19] += p*f.y; \
            f = __half22float2(__builtin_bit_cast(__half2, (r2).z)); acc[20] += p*f.x; acc[21] += p*f.y; \
            f = __half22float2(__builtin_bit_cast(__half2, (r2).w)); acc[22] += p*f.x; acc[23] += p*f.y; \
            f = __half22float2(__builtin_bit_cast(__half2, (r3).x)); acc[24] += p*f.x; acc[25] += p*f.y; \
            f = __half22float2(__builtin_bit_cast(__half2, (r3).y)); acc[26] += p*f.x; acc[27] += p*f.y; \
            f = __half22float2(__builtin_bit_cast(__half2, (r3).z)); acc[28] += p*f.x; acc[29] += p*f.y; }
        if (fit) {
            unsigned beg = pr[j], end = beg + h[j];
            unsigned i = beg + half;                 // this half's edges: stride 2
            for (; i + 2 < end; i += 4) {            // 2 rows in flight
                unsigned sA = sBuf[i], sB = sBuf[i + 2];
                const float4* zA = (const float4*)(z2h + (size_t)sA * 32);
                const float4* zB = (const float4*)(z2h + (size_t)sB * 32);
                float4 a0 = zA[0], a1 = zA[1], a2 = zA[2], a3 = zA[3];
                float4 b0 = zB[0], b1 = zB[1], b2 = zB[2], b3 = zB[3];
                PROC(a0, a1, a2, a3)
                PROC(b0, b1, b2, b3)
            }
            if (i < end) {
                unsigned s = sBuf[i];
                const float4* zr = (const float4*)(z2h + (size_t)s * 32);
                float4 r0 = zr[0], r1 = zr[1], r2 = zr[2], r3 = zr[3];
                PROC(r0, r1, r2, r3)
            }
        } else if (half == 0) {                      // exact fallback (never here)
            for (unsigned i = bb; i < be; ++i) {
                unsigned w = pck[i];
                if ((int)(w >> 17) == j) {
                    unsigned s = w & 0x1FFFFu;
                    const float4* zr = (const float4*)(z2h + (size_t)s * 32);
                    float4 r0 = zr[0], r1 = zr[1], r2 = zr[2], r3 = zr[3];
                    PROC(r0, r1, r2, r3)
                }
            }
        }
#undef PROC
    }
    xsp[half][j] = sp;
    __syncthreads();
    float spTot = xsp[0][j] + xsp[1][j];
    float inv = (spTot > 0.f) ? 1.f / spTot : 0.f;
#pragma unroll
    for (int q = 0; q < 30; ++q) acc[q] *= inv;
#pragma unroll
    for (int q = 0; q < 30; ++q)
        for (int off = 32; off > 0; off >>= 1) acc[q] += __shfl_down(acc[q], off);
    if (lane == 0) {
#pragma unroll
        for (int q = 0; q < 30; ++q) shr[wv][q] = acc[q];
    }
    __syncthreads();
    if (tid < 30) {
        float s = 0.f;
#pragma unroll
        for (int w8 = 0; w8 < 8; ++w8) s += shr[w8][tid];
        atomicAdd(&acc_g[tid], s);          // device-scope: cross-XCD coherent
    }
    __threadfence();
    if (tid == 0) {
        unsigned t = atomicAdd(ctr, 1u);    // ticket; last block runs epilogue
        isLast = (t == NBKT - 1u) ? 1 : 0;
    }
    __syncthreads();
    if (!isLast) return;

    // ---------- k6 epilogue (last block only; same arithmetic as before) ----------
    {
        int r = tid >> 3, sub = tid & 7;
        float pt = 0.f;
        if (tid < 256 && r < 30) {
            for (int k = 0; k < 64; ++k) pt += W_lin1[r*512 + sub + k*8] * x[sub + k*8];
        }
        if (tid < 256) sh6[tid] = pt;
        __syncthreads();
        if (tid < 30) {
            float hi = 0.f;
            for (int i = 0; i < 8; ++i) hi += sh6[tid*8 + i];
            float acc6 = 0.f;
            for (int k = 0; k < 64; ++k) acc6 += w3c[k] / (1.f + __expf(-w2c[k] * hi));
            hvec[30 + tid] = 1.f / (1.f + __expf(-acc6));
            float cs = atomicAdd(&acc_g[tid], 0.f);   // coherent read of total colsum
            hvec[tid] = cs * (1.0f / (float)NN) + b2v[tid];
        }
        if (tid >= 64 && tid < 74) hvec[60 + (tid - 64)] = vocab[tid - 64];
        __syncthreads();
        if (tid == 0) {
            float p0 = 0.f, p1 = 0.f;
            for (int k = 0; k < 70; ++k) {
                p0 += W4[k] * hvec[k];
                p1 += W4[70 + k] * hvec[k];
            }
            float mx = fmaxf(p0, p1);
            float l = logf(__expf(p0 - mx) + __expf(p1 - mx));
            out[0] = p0 - mx - l;
            out[1] = p1 - mx - l;
        }
    }
}

extern "C" void kernel_launch(void* const* d_in, const int* in_sizes, int n_in,
                              void* d_out, int out_size, void* d_ws, size_t ws_size,
                              hipStream_t stream) {
    const float* x      = (const float*)d_in[0];
    const float* feat   = (const float*)d_in[1];
    const float* vocab  = (const float*)d_in[2];
    const int*   src    = (const int*)d_in[3];
    const int*   dst    = (const int*)d_in[4];
    const float* W_lin1 = (const float*)d_in[5];
    const float* w_c2   = (const float*)d_in[6];
    const float* w_c3   = (const float*)d_in[7];
    const float* W_lin4 = (const float*)d_in[8];
    const float* W1     = (const float*)d_in[9];
    const float* al1    = (const float*)d_in[10];
    const float* ar1    = (const float*)d_in[11];
    const float* b1     = (const float*)d_in[12];
    const float* W2     = (const float*)d_in[13];
    const float* al2    = (const float*)d_in[14];
    const float* ar2    = (const float*)d_in[15];
    const float* b2     = (const float*)d_in[16];
    float* out = (float*)d_out;
    float* w = (float*)d_ws;

    float4*   pfeat = (float4*)(w + OFF_PFEAT);
    float*    er1   = w + OFF_ER1;
    float*    er2   = w + OFF_ER2;
    unsigned* tot   = (unsigned*)(w + OFF_TOT);
    unsigned* bbase = (unsigned*)(w + OFF_BBASE);
    unsigned* HT    = (unsigned*)(w + OFF_HT);
    unsigned* pck   = (unsigned*)(w + OFF_PCK);
    __half*   z2h   = (__half*)(w + OFF_Z2H);
    float*    accg  = w + OFF_ACC;
    unsigned* ctr   = (unsigned*)(w + OFF_CTR);

    kA_hist<<<NBLK, 256, 0, stream>>>(dst, feat, W1, al1, ar1, HT, pfeat, er1);
    kB_scan<<<NBKT, 256, 0, stream>>>(HT, tot, accg, ctr);
    kC_scatter<<<NBLK, 256, 0, stream>>>(src, dst, HT, tot, bbase, pck);
    kG1_node<<<NBKT, 512, 0, stream>>>(bbase, pck, pfeat, er1, W1, b1, W2, al2, ar2, z2h, er2);
    kG2_layer2<<<NBKT, 512, 0, stream>>>(bbase, pck, z2h, er2, accg, ctr,
                                         x, vocab, W_lin1, w_c2, w_c3, W_lin4, b2, out);
}

// Round 12
// 183.842 us; speedup vs baseline: 1.2207x; 1.2207x over previous
//
#include <hip/hip_runtime.h>
#include <hip/hip_bf16.h>
#include <hip/hip_fp16.h>

#define NN 100000      // nodes
#define NE 1000000     // edges
#define EPB 2048       // edges per block in edge passes
#define NBLK 489       // ceil(NE/EPB)
#define NBKT 391       // buckets: bucket = dst>>8 (256 nodes each) == consumer blocks
#define HSTR 392       // HT row stride in u32 (HT[block][bucket])
#define SCAP 6144      // LDS edge-buffer capacity per bucket (avg 2560, max ~2800)

// ---------------- workspace layout (4-byte units) ----------------
#define OFF_PFEAT    0              // float4[NN] {f0,f1,f2,el1}
#define OFF_ER1      400000         // f32[NN]
#define OFF_ER2      500000         // f32[NN]
#define OFF_TOT      600000         // u32[NBKT]
#define OFF_BBASE    600391         // u32[NBKT+1]  (published by kC block 0)
#define OFF_HT       600784         // u32[NBLK*HSTR]  HT[block][bucket]
#define OFF_PCK      792472         // u32[NE] bucket-partitioned packed {dstlocal:8|src:17}
#define OFF_OFFS     1792472        // u32[NN+1]  CSR offsets (exported by kG1)
#define OFF_BSRC     1892476        // u32[NE]    sorted src (exported by kG1)
#define OFF_Z2H      2892476        // half[32*NN] (64B rows; [30]=el2) 16B-aligned
#define OFF_PARTS    4492476        // f32[NBKT*32]

#define PK2(a,b) __builtin_bit_cast(float, __floats2half2_rn((a),(b)))

// pass A: per-block LDS histogram over 391 buckets (8 edges/thread);
// coalesced HT row write. Each block computes cl/cr itself; low blocks pack pfeat/er1.
__global__ void kA_hist(const int* __restrict__ dst, const float* __restrict__ feat,
                        const float* __restrict__ W1, const float* __restrict__ al1,
                        const float* __restrict__ ar1, unsigned* __restrict__ HT,
                        float4* __restrict__ pfeat, float* __restrict__ er1) {
    __shared__ unsigned h[NBKT];
    __shared__ float scl[3], scr[3];
    int tid = threadIdx.x;
    if (tid < 64) {
        float a = al1[tid], r = ar1[tid];
#pragma unroll
        for (int k = 0; k < 3; ++k) {
            float wv = W1[k*128 + tid];
            float vl = wv * a, vr = wv * r;
            for (int off = 32; off > 0; off >>= 1) {
                vl += __shfl_down(vl, off);
                vr += __shfl_down(vr, off);
            }
            if (tid == 0) { scl[k] = vl; scr[k] = vr; }
        }
    }
    for (int i = tid; i < NBKT; i += 256) h[i] = 0u;
    __syncthreads();
    int e0 = blockIdx.x * EPB + tid * 8;
    if (e0 + 8 <= NE) {
        int4 da = *(const int4*)(dst + e0);
        int4 db = *(const int4*)(dst + e0 + 4);
        atomicAdd(&h[da.x >> 8], 1u); atomicAdd(&h[da.y >> 8], 1u);
        atomicAdd(&h[da.z >> 8], 1u); atomicAdd(&h[da.w >> 8], 1u);
        atomicAdd(&h[db.x >> 8], 1u); atomicAdd(&h[db.y >> 8], 1u);
        atomicAdd(&h[db.z >> 8], 1u); atomicAdd(&h[db.w >> 8], 1u);
    } else {
        for (int e = e0; e < NE; ++e) atomicAdd(&h[dst[e] >> 8], 1u);
    }
    int n = blockIdx.x * 256 + tid;
    if (n < NN) {
        float f0 = feat[n*3], f1 = feat[n*3+1], f2 = feat[n*3+2];
        pfeat[n] = make_float4(f0, f1, f2, f0*scl[0] + f1*scl[1] + f2*scl[2]);
        er1[n] = f0*scr[0] + f1*scr[1] + f2*scr[2];
    }
    __syncthreads();
    unsigned* row = HT + (size_t)blockIdx.x * HSTR;
    for (int k = tid; k < NBKT; k += 256) row[k] = h[k];
}

// pass B: one block per bucket: exclusive scan over NBLK=489 blocks (2/thread) + total
__global__ void kB_scan(unsigned* __restrict__ HT, unsigned* __restrict__ tot) {
    __shared__ unsigned sh[256];
    int t = threadIdx.x;
    int kb = blockIdx.x;
    int b0 = 2*t, b1 = 2*t + 1;
    unsigned v0 = (b0 < NBLK) ? HT[(size_t)b0 * HSTR + kb] : 0u;
    unsigned v1 = (b1 < NBLK) ? HT[(size_t)b1 * HSTR + kb] : 0u;
    unsigned s = v0 + v1;
    sh[t] = s;
    __syncthreads();
    for (int off = 1; off < 256; off <<= 1) {
        unsigned u = (t >= off) ? sh[t - off] : 0u;
        __syncthreads();
        sh[t] += u;
        __syncthreads();
    }
    unsigned base = sh[t] - s;
    if (b0 < NBLK) HT[(size_t)b0 * HSTR + kb] = base;
    if (b1 < NBLK) HT[(size_t)b1 * HSTR + kb] = base + v0;
    if (t == 255) tot[kb] = sh[255];
}

// pass C: rank edges per (block,bucket) via LDS atomics (8 edges/thread), LDS-sort
// by bucket, write bucket-sorted runs. Computes bbase in-LDS from tot; block 0
// publishes it.
__global__ void kC_scatter(const int* __restrict__ src, const int* __restrict__ dst,
                           const unsigned* __restrict__ HT, const unsigned* __restrict__ tot,
                           unsigned* __restrict__ bbase, unsigned* __restrict__ pck) {
    __shared__ unsigned sCnt[NBKT];
    __shared__ unsigned sPos[NBKT];
    __shared__ unsigned sBB[NBKT];
    __shared__ unsigned sDelta[NBKT];
    __shared__ unsigned sBuf[EPB];
    __shared__ unsigned short sBkt[EPB];
    __shared__ unsigned sh[256];
    int tid = threadIdx.x;
    for (int k = tid; k < NBKT; k += 256) sCnt[k] = 0u;
    __syncthreads();
    int vcnt = NE - blockIdx.x * EPB;
    if (vcnt > EPB) vcnt = EPB;
    int e0 = blockIdx.x * EPB + tid * 8;
    int nv = vcnt - tid * 8;                // valid edges for this thread (of 8)
    int cnt8 = (nv >= 8) ? 8 : ((nv > 0) ? nv : 0);
    unsigned wE[8], bE[8], rE[8];
    if (nv >= 8) {
        int4 sa = *(const int4*)(src + e0);
        int4 sb = *(const int4*)(src + e0 + 4);
        int4 da = *(const int4*)(dst + e0);
        int4 db = *(const int4*)(dst + e0 + 4);
        int ss[8] = {sa.x, sa.y, sa.z, sa.w, sb.x, sb.y, sb.z, sb.w};
        int dd[8] = {da.x, da.y, da.z, da.w, db.x, db.y, db.z, db.w};
#pragma unroll
        for (int q = 0; q < 8; ++q) {
            unsigned d = (unsigned)dd[q];
            bE[q] = d >> 8;
            rE[q] = atomicAdd(&sCnt[bE[q]], 1u);
            wE[q] = (unsigned)ss[q] | ((d & 255u) << 17);
        }
    } else if (cnt8 > 0) {
#pragma unroll
        for (int q = 0; q < 8; ++q) {
            if (q < cnt8) {
                unsigned d = (unsigned)dst[e0 + q];
                bE[q] = d >> 8;
                rE[q] = atomicAdd(&sCnt[bE[q]], 1u);
                wE[q] = (unsigned)src[e0 + q] | ((d & 255u) << 17);
            }
        }
    }
    __syncthreads();
    // scan 1: sCnt -> sPos (exclusive within block)
    unsigned c0 = (2*tid     < NBKT) ? sCnt[2*tid]     : 0u;
    unsigned c1 = (2*tid + 1 < NBKT) ? sCnt[2*tid + 1] : 0u;
    unsigned ssum = c0 + c1;
    sh[tid] = ssum;
    __syncthreads();
    for (int off = 1; off < 256; off <<= 1) {
        unsigned u = (tid >= off) ? sh[tid - off] : 0u;
        __syncthreads();
        sh[tid] += u;
        __syncthreads();
    }
    unsigned base = sh[tid] - ssum;
    if (2*tid     < NBKT) sPos[2*tid]     = base;
    if (2*tid + 1 < NBKT) sPos[2*tid + 1] = base + c0;
    __syncthreads();
#pragma unroll
    for (int q = 0; q < 8; ++q) {
        if (q < cnt8) {
            unsigned i = sPos[bE[q]] + rE[q];
            sBuf[i] = wE[q];
            sBkt[i] = (unsigned short)bE[q];
        }
    }
    // scan 2: tot -> sBB (bucket bases)
    unsigned t0 = (2*tid     < NBKT) ? tot[2*tid]     : 0u;
    unsigned t1 = (2*tid + 1 < NBKT) ? tot[2*tid + 1] : 0u;
    unsigned ss2 = t0 + t1;
    sh[tid] = ss2;
    __syncthreads();
    for (int off = 1; off < 256; off <<= 1) {
        unsigned u = (tid >= off) ? sh[tid - off] : 0u;
        __syncthreads();
        sh[tid] += u;
        __syncthreads();
    }
    unsigned b2x = sh[tid] - ss2;
    if (2*tid     < NBKT) sBB[2*tid]     = b2x;
    if (2*tid + 1 < NBKT) sBB[2*tid + 1] = b2x + t0;
    __syncthreads();
    if (blockIdx.x == 0) {
        for (int k = tid; k < NBKT; k += 256) bbase[k] = sBB[k];
        if (tid == 0) bbase[NBKT] = NE;
    }
    {
        const unsigned* row = HT + (size_t)blockIdx.x * HSTR;
        for (int k = tid; k < NBKT; k += 256)
            sDelta[k] = sBB[k] + row[k] - sPos[k];
    }
    __syncthreads();
    for (int i = tid; i < vcnt; i += 256)
        pck[i + sDelta[sBkt[i]]] = sBuf[i];
}

// kG1: 512 threads per bucket. LDS sort ONCE; export sorted bsrc + offsets so kG2
// can skip its sort. Then 2 threads/node consume interleaved halves; per-node MLP
// -> z2 row (fp16) + er2 on threads <256.
__global__ void kG1_node(const unsigned* __restrict__ bbase, const unsigned* __restrict__ pck,
                         const float4* __restrict__ pfeat, const float* __restrict__ er1,
                         const float* __restrict__ W1, const float* __restrict__ b1,
                         const float* __restrict__ W2, const float* __restrict__ al2,
                         const float* __restrict__ ar2,
                         __half* __restrict__ z2h, float* __restrict__ er2,
                         unsigned* __restrict__ bsrc, unsigned* __restrict__ offsets) {
    __shared__ float sW1[192], sb1[64], sW2[1920], sal2[30], sar2[30];
    __shared__ unsigned h[256], pr[256], cur[256];
    __shared__ unsigned sBuf[SCAP];
    __shared__ float xch[4][256];
    int tid = threadIdx.x;
    for (int i = tid; i < 192; i += 512) sW1[i] = W1[(i >> 6)*128 + (i & 63)];
    for (int i = tid; i < 1920; i += 512) sW2[i] = W2[(i / 30)*60 + (i % 30)];
    if (tid < 64) sb1[tid] = b1[tid];
    if (tid < 30) { sal2[tid] = al2[tid]; sar2[tid] = ar2[tid]; }
    unsigned bb = bbase[blockIdx.x], be = bbase[blockIdx.x + 1];
    unsigned cnt = be - bb;
    bool fit = (cnt <= SCAP);               // block-uniform
    if (tid < 256) { h[tid] = 0u; cur[tid] = 0u; }
    __syncthreads();
    if (fit) {
        for (unsigned i = bb + tid; i < be; i += 512) atomicAdd(&h[pck[i] >> 17], 1u);
        __syncthreads();
        unsigned v = 0;
        if (tid < 256) { v = h[tid]; pr[tid] = v; }
        __syncthreads();
        for (int off = 1; off < 256; off <<= 1) {
            unsigned u = 0;
            if (tid < 256 && tid >= off) u = pr[tid - off];
            __syncthreads();
            if (tid < 256) pr[tid] += u;
            __syncthreads();
        }
        if (tid < 256) pr[tid] -= v;
        __syncthreads();
        for (unsigned i = bb + tid; i < be; i += 512) {
            unsigned w = pck[i];
            unsigned j = w >> 17;
            unsigned r = atomicAdd(&cur[j], 1u);
            sBuf[pr[j] + r] = w & 0x1FFFFu;
        }
        __syncthreads();
        // export: sorted src list (coalesced) + per-node offsets for kG2
        for (unsigned i = tid; i < cnt; i += 512) bsrc[bb + i] = sBuf[i];
        if (tid < 256) {
            int node = blockIdx.x * 256 + tid;
            if (node < NN) offsets[node] = bb + pr[tid];
            else if (node == NN) offsets[NN] = NE;
        }
        if (blockIdx.x == NBKT - 1 && tid == 160) offsets[NN] = NE;  // node==NN slot
    }
    int j = tid & 255, half = tid >> 8;
    int n = blockIdx.x * 256 + j;
    bool valid = (n < NN);
    float s0 = 0.f, s1 = 0.f, s2 = 0.f, sp = 0.f;
    if (valid) {
        float erd = er1[n];
        if (fit) {
            unsigned beg = pr[j], end = beg + h[j];
            unsigned i = beg + half;                 // this half's edges: stride 2
            for (; i + 2 < end; i += 4) {            // 2 gathers in flight
                unsigned sA = sBuf[i], sB = sBuf[i + 2];
                float4 vA = pfeat[sA], vB = pfeat[sB];
                float eA = vA.w + erd; eA = (eA >= 0.f) ? eA : 0.2f*eA; float pA = __expf(eA);
                s0 += pA*vA.x; s1 += pA*vA.y; s2 += pA*vA.z; sp += pA;
                float eB = vB.w + erd; eB = (eB >= 0.f) ? eB : 0.2f*eB; float pB = __expf(eB);
                s0 += pB*vB.x; s1 += pB*vB.y; s2 += pB*vB.z; sp += pB;
            }
            if (i < end) {
                unsigned s = sBuf[i];
                float4 v = pfeat[s];
                float ee = v.w + erd; ee = (ee >= 0.f) ? ee : 0.2f*ee; float p = __expf(ee);
                s0 += p*v.x; s1 += p*v.y; s2 += p*v.z; sp += p;
            }
        } else if (half == 0) {                      // exact fallback (never here)
            for (unsigned i = bb; i < be; ++i) {
                unsigned w = pck[i];
                if ((int)(w >> 17) == j) {
                    float4 v = pfeat[w & 0x1FFFFu];
                    float ee = v.w + erd; ee = (ee >= 0.f) ? ee : 0.2f*ee; float p = __expf(ee);
                    s0 += p*v.x; s1 += p*v.y; s2 += p*v.z; sp += p;
                }
            }
        }
    }
    if (half == 1) { xch[0][j] = s0; xch[1][j] = s1; xch[2][j] = s2; xch[3][j] = sp; }
    __syncthreads();
    if (tid >= 256 || !valid) return;
    s0 += xch[0][tid]; s1 += xch[1][tid]; s2 += xch[2][tid]; sp += xch[3][tid];
    float inv = (sp > 0.f) ? 1.f / sp : 0.f;
    float ax = s0 * inv, ay = s1 * inv, az = s2 * inv;
    float z[30];
#pragma unroll
    for (int c = 0; c < 30; ++c) z[c] = 0.f;
    for (int jj = 0; jj < 64; ++jj) {
        float rj = fmaxf(ax*sW1[jj] + ay*sW1[64 + jj] + az*sW1[128 + jj] + sb1[jj], 0.f);
#pragma unroll
        for (int c = 0; c < 30; ++c) z[c] += rj * sW2[jj*30 + c];
    }
    float sl = 0.f, sr = 0.f;
#pragma unroll
    for (int c = 0; c < 30; ++c) { sl += z[c] * sal2[c]; sr += z[c] * sar2[c]; }
    float4* outp = (float4*)(z2h + (size_t)n * 32);
    outp[0] = make_float4(PK2(z[0],z[1]),  PK2(z[2],z[3]),  PK2(z[4],z[5]),  PK2(z[6],z[7]));
    outp[1] = make_float4(PK2(z[8],z[9]),  PK2(z[10],z[11]),PK2(z[12],z[13]),PK2(z[14],z[15]));
    outp[2] = make_float4(PK2(z[16],z[17]),PK2(z[18],z[19]),PK2(z[20],z[21]),PK2(z[22],z[23]));
    outp[3] = make_float4(PK2(z[24],z[25]),PK2(z[26],z[27]),PK2(z[28],z[29]),PK2(sl, 0.f));
    er2[n] = sr;
}

// kG2: 512 threads per bucket. NO sort — stage pre-sorted bsrc into LDS (coalesced),
// consume with offsets; 2 threads/node interleaved halves; block reduce -> partials.
__global__ void kG2_layer2(const unsigned* __restrict__ bbase, const unsigned* __restrict__ pck,
                           const unsigned* __restrict__ bsrc, const unsigned* __restrict__ offsets,
                           const __half* __restrict__ z2h, const float* __restrict__ er2,
                           float* __restrict__ part) {
    __shared__ unsigned sBuf[SCAP];
    __shared__ float xsp[2][256];
    __shared__ float shr[8][32];
    int tid = threadIdx.x;
    int lane = tid & 63, wv = tid >> 6;   // 8 waves
    unsigned bb = bbase[blockIdx.x], be = bbase[blockIdx.x + 1];
    unsigned cnt = be - bb;
    bool fit = (cnt <= SCAP);
    if (fit) {
        for (unsigned i = tid; i < cnt; i += 512) sBuf[i] = bsrc[bb + i];
        __syncthreads();
    }
    int j = tid & 255, half = tid >> 8;
    int n = blockIdx.x * 256 + j;
    bool valid = (n < NN);
    float acc[30];
#pragma unroll
    for (int q = 0; q < 30; ++q) acc[q] = 0.f;
    float sp = 0.f;
    if (valid) {
        float erd = er2[n];
#define PROC(r0, r1, r2, r3) { \
            float el = __half2float(__low2half(__builtin_bit_cast(__half2, (r3).w))); \
            float ee = el + erd; \
            ee = (ee >= 0.f) ? ee : 0.2f * ee; \
            float p = __expf(ee); \
            sp += p; \
            float2 f; \
            f = __half22float2(__builtin_bit_cast(__half2, (r0).x)); acc[0]  += p*f.x; acc[1]  += p*f.y; \
            f = __half22float2(__builtin_bit_cast(__half2, (r0).y)); acc[2]  += p*f.x; acc[3]  += p*f.y; \
            f = __half22float2(__builtin_bit_cast(__half2, (r0).z)); acc[4]  += p*f.x; acc[5]  += p*f.y; \
            f = __half22float2(__builtin_bit_cast(__half2, (r0).w)); acc[6]  += p*f.x; acc[7]  += p*f.y; \
            f = __half22float2(__builtin_bit_cast(__half2, (r1).x)); acc[8]  += p*f.x; acc[9]  += p*f.y; \
            f = __half22float2(__builtin_bit_cast(__half2, (r1).y)); acc[10] += p*f.x; acc[11] += p*f.y; \
            f = __half22float2(__builtin_bit_cast(__half2, (r1).z)); acc[12] += p*f.x; acc[13] += p*f.y; \
            f = __half22float2(__builtin_bit_cast(__half2, (r1).w)); acc[14] += p*f.x; acc[15] += p*f.y; \
            f = __half22float2(__builtin_bit_cast(__half2, (r2).x)); acc[16] += p*f.x; acc[17] += p*f.y; \
            f = __half22float2(__builtin_bit_cast(__half2, (r2).y)); acc[18] += p*f.x; acc[19] += p*f.y; \
            f = __half22float2(__builtin_bit_cast(__half2, (r2).z)); acc[20] += p*f.x; acc[21] += p*f.y; \
            f = __half22float2(__builtin_bit_cast(__half2, (r2).w)); acc[22] += p*f.x; acc[23] += p*f.y; \
            f = __half22float2(__builtin_bit_cast(__half2, (r3).x)); acc[24] += p*f.x; acc[25] += p*f.y; \
            f = __half22float2(__builtin_bit_cast(__half2, (r3).y)); acc[26] += p*f.x; acc[27] += p*f.y; \
            f = __half22float2(__builtin_bit_cast(__half2, (r3).z)); acc[28] += p*f.x; acc[29] += p*f.y; }
        if (fit) {
            unsigned beg = offsets[n] - bb;
            unsigned end = ((j == 255) ? be : offsets[n + 1]) - bb;
            unsigned i = beg + half;                 // this half's edges: stride 2
            for (; i + 2 < end; i += 4) {            // 2 rows in flight
                unsigned sA = sBuf[i], sB = sBuf[i + 2];
                const float4* zA = (const float4*)(z2h + (size_t)sA * 32);
                const float4* zB = (const float4*)(z2h + (size_t)sB * 32);
                float4 a0 = zA[0], a1 = zA[1], a2 = zA[2], a3 = zA[3];
                float4 b0 = zB[0], b1 = zB[1], b2 = zB[2], b3 = zB[3];
                PROC(a0, a1, a2, a3)
                PROC(b0, b1, b2, b3)
            }
            if (i < end) {
                unsigned s = sBuf[i];
                const float4* zr = (const float4*)(z2h + (size_t)s * 32);
                float4 r0 = zr[0], r1 = zr[1], r2 = zr[2], r3 = zr[3];
                PROC(r0, r1, r2, r3)
            }
        } else if (half == 0) {                      // exact fallback (never here)
            for (unsigned i = bb; i < be; ++i) {
                unsigned w = pck[i];
                if ((int)(w >> 17) == j) {
                    unsigned s = w & 0x1FFFFu;
                    const float4* zr = (const float4*)(z2h + (size_t)s * 32);
                    float4 r0 = zr[0], r1 = zr[1], r2 = zr[2], r3 = zr[3];
                    PROC(r0, r1, r2, r3)
                }
            }
        }
#undef PROC
    }
    xsp[half][j] = sp;
    __syncthreads();
    float spTot = xsp[0][j] + xsp[1][j];
    float inv = (spTot > 0.f) ? 1.f / spTot : 0.f;
#pragma unroll
    for (int q = 0; q < 30; ++q) acc[q] *= inv;
#pragma unroll
    for (int q = 0; q < 30; ++q)
        for (int off = 32; off > 0; off >>= 1) acc[q] += __shfl_down(acc[q], off);
    if (lane == 0) {
#pragma unroll
        for (int q = 0; q < 30; ++q) shr[wv][q] = acc[q];
    }
    __syncthreads();
    if (tid < 30) {
        float s = 0.f;
#pragma unroll
        for (int w8 = 0; w8 < 8; ++w8) s += shr[w8][tid];
        part[blockIdx.x * 32 + tid] = s;
    }
}

// single block: image path, sum partials, a00 = colsum/N + b2, concat, log_softmax
__global__ void k6_final(const float* __restrict__ x, const float* __restrict__ vocab,
                         const float* __restrict__ W_lin1, const float* __restrict__ w2,
                         const float* __restrict__ w3, const float* __restrict__ W4,
                         const float* __restrict__ b2, const float* __restrict__ part,
                         float* __restrict__ out) {
    __shared__ float sh[256];
    __shared__ float hvec[70];
    int tid = threadIdx.x;
    int r = tid >> 3, sub = tid & 7;
    float pt = 0.f;
    if (r < 30) {
        for (int k = sub; k < 512; k += 8) pt += W_lin1[r*512 + k] * x[k];
    }
    sh[tid] = pt;
    __syncthreads();
    if (tid < 30) {
        float hi = 0.f;
        for (int i = 0; i < 8; ++i) hi += sh[tid*8 + i];
        float acc = 0.f;
        for (int k = 0; k < 64; ++k) acc += w3[k] / (1.f + __expf(-w2[k] * hi));
        hvec[30 + tid] = 1.f / (1.f + __expf(-acc));
        float cs = 0.f;
        for (int b = 0; b < NBKT; ++b) cs += part[b*32 + tid];
        hvec[tid] = cs * (1.0f / (float)NN) + b2[tid];
    }
    if (tid >= 64 && tid < 74) hvec[60 + (tid - 64)] = vocab[tid - 64];
    __syncthreads();
    if (tid == 0) {
        float p0 = 0.f, p1 = 0.f;
        for (int k = 0; k < 70; ++k) {
            p0 += W4[k] * hvec[k];
            p1 += W4[70 + k] * hvec[k];
        }
        float mx = fmaxf(p0, p1);
        float l = logf(__expf(p0 - mx) + __expf(p1 - mx));
        out[0] = p0 - mx - l;
        out[1] = p1 - mx - l;
    }
}

extern "C" void kernel_launch(void* const* d_in, const int* in_sizes, int n_in,
                              void* d_out, int out_size, void* d_ws, size_t ws_size,
                              hipStream_t stream) {
    const float* x      = (const float*)d_in[0];
    const float* feat   = (const float*)d_in[1];
    const float* vocab  = (const float*)d_in[2];
    const int*   src    = (const int*)d_in[3];
    const int*   dst    = (const int*)d_in[4];
    const float* W_lin1 = (const float*)d_in[5];
    const float* w_c2   = (const float*)d_in[6];
    const float* w_c3   = (const float*)d_in[7];
    const float* W_lin4 = (const float*)d_in[8];
    const float* W1     = (const float*)d_in[9];
    const float* al1    = (const float*)d_in[10];
    const float* ar1    = (const float*)d_in[11];
    const float* b1     = (const float*)d_in[12];
    const float* W2     = (const float*)d_in[13];
    const float* al2    = (const float*)d_in[14];
    const float* ar2    = (const float*)d_in[15];
    const float* b2     = (const float*)d_in[16];
    float* out = (float*)d_out;
    float* w = (float*)d_ws;

    float4*   pfeat   = (float4*)(w + OFF_PFEAT);
    float*    er1     = w + OFF_ER1;
    float*    er2     = w + OFF_ER2;
    unsigned* tot     = (unsigned*)(w + OFF_TOT);
    unsigned* bbase   = (unsigned*)(w + OFF_BBASE);
    unsigned* HT      = (unsigned*)(w + OFF_HT);
    unsigned* pck     = (unsigned*)(w + OFF_PCK);
    unsigned* offsets = (unsigned*)(w + OFF_OFFS);
    unsigned* bsrc    = (unsigned*)(w + OFF_BSRC);
    __half*   z2h     = (__half*)(w + OFF_Z2H);
    float*    part    = w + OFF_PARTS;

    kA_hist<<<NBLK, 256, 0, stream>>>(dst, feat, W1, al1, ar1, HT, pfeat, er1);
    kB_scan<<<NBKT, 256, 0, stream>>>(HT, tot);
    kC_scatter<<<NBLK, 256, 0, stream>>>(src, dst, HT, tot, bbase, pck);
    kG1_node<<<NBKT, 512, 0, stream>>>(bbase, pck, pfeat, er1, W1, b1, W2, al2, ar2,
                                       z2h, er2, bsrc, offsets);
    kG2_layer2<<<NBKT, 512, 0, stream>>>(bbase, pck, bsrc, offsets, z2h, er2, part);
    k6_final<<<1, 256, 0, stream>>>(x, vocab, W_lin1, w_c2, w_c3, W_lin4, b2, part, out);
}

// Round 13
// 182.426 us; speedup vs baseline: 1.2302x; 1.0078x over previous
//
#include <hip/hip_runtime.h>
#include <hip/hip_bf16.h>
#include <hip/hip_fp16.h>

#define NN 100000      // nodes
#define NE 1000000     // edges
#define EPB 4096       // edges per block in edge passes
#define NBLK 245       // ceil(NE/EPB)
#define NBKT 391       // buckets: bucket = dst>>8 (256 nodes each) == consumer blocks
#define HSTR 392       // HT row stride in u32 (HT[block][bucket])
#define SCAP 6144      // LDS edge-buffer capacity per bucket (avg 2560, max ~2800)

// ---------------- workspace layout (4-byte units) ----------------
#define OFF_PFEAT    0              // float4[NN] {f0,f1,f2,el1}
#define OFF_ER1      400000         // f32[NN]
#define OFF_ER2      500000         // f32[NN]
#define OFF_TOT      600000         // u32[NBKT]
#define OFF_BBASE    600391         // u32[NBKT+1]  (published by kC block 0)
#define OFF_HT       600784         // u32[NBLK*HSTR]  HT[block][bucket]
#define OFF_PCK      696824         // u32[NE] bucket-partitioned packed {dstlocal:8|src:17}
#define OFF_OFFS     1696824        // u32[NN+1]  CSR offsets (exported by kG1)
#define OFF_BSRC     1796828        // u32[NE]    sorted src (exported by kG1)
#define OFF_Z2H      2796828        // half[32*NN] (64B rows; [30]=el2) 16B-aligned
#define OFF_PARTS    4396828        // f32[NBKT*32]

#define PK2(a,b) __builtin_bit_cast(float, __floats2half2_rn((a),(b)))

// pass A: 512 threads, 8 edges/thread LDS histogram over 391 buckets; coalesced HT
// row write. Each block computes cl/cr itself; low blocks pack pfeat/er1.
__global__ void kA_hist(const int* __restrict__ dst, const float* __restrict__ feat,
                        const float* __restrict__ W1, const float* __restrict__ al1,
                        const float* __restrict__ ar1, unsigned* __restrict__ HT,
                        float4* __restrict__ pfeat, float* __restrict__ er1) {
    __shared__ unsigned h[NBKT];
    __shared__ float scl[3], scr[3];
    int tid = threadIdx.x;
    if (tid < 64) {
        float a = al1[tid], r = ar1[tid];
#pragma unroll
        for (int k = 0; k < 3; ++k) {
            float wv = W1[k*128 + tid];
            float vl = wv * a, vr = wv * r;
            for (int off = 32; off > 0; off >>= 1) {
                vl += __shfl_down(vl, off);
                vr += __shfl_down(vr, off);
            }
            if (tid == 0) { scl[k] = vl; scr[k] = vr; }
        }
    }
    for (int i = tid; i < NBKT; i += 512) h[i] = 0u;
    __syncthreads();
    int e0 = blockIdx.x * EPB + tid * 8;
    if (e0 + 8 <= NE) {
        int4 da = *(const int4*)(dst + e0);
        int4 db = *(const int4*)(dst + e0 + 4);
        atomicAdd(&h[da.x >> 8], 1u); atomicAdd(&h[da.y >> 8], 1u);
        atomicAdd(&h[da.z >> 8], 1u); atomicAdd(&h[da.w >> 8], 1u);
        atomicAdd(&h[db.x >> 8], 1u); atomicAdd(&h[db.y >> 8], 1u);
        atomicAdd(&h[db.z >> 8], 1u); atomicAdd(&h[db.w >> 8], 1u);
    } else {
        for (int e = e0; e < NE; ++e) atomicAdd(&h[dst[e] >> 8], 1u);
    }
    int n = blockIdx.x * 512 + tid;
    if (n < NN) {
        float f0 = feat[n*3], f1 = feat[n*3+1], f2 = feat[n*3+2];
        pfeat[n] = make_float4(f0, f1, f2, f0*scl[0] + f1*scl[1] + f2*scl[2]);
        er1[n] = f0*scr[0] + f1*scr[1] + f2*scr[2];
    }
    __syncthreads();
    unsigned* row = HT + (size_t)blockIdx.x * HSTR;
    for (int k = tid; k < NBKT; k += 512) row[k] = h[k];
}

// pass B: one block per bucket: exclusive scan over NBLK=245 blocks (1/thread) + total
__global__ void kB_scan(unsigned* __restrict__ HT, unsigned* __restrict__ tot) {
    __shared__ unsigned sh[256];
    int t = threadIdx.x;
    int kb = blockIdx.x;
    unsigned v = (t < NBLK) ? HT[(size_t)t * HSTR + kb] : 0u;
    sh[t] = v;
    __syncthreads();
    for (int off = 1; off < 256; off <<= 1) {
        unsigned u = (t >= off) ? sh[t - off] : 0u;
        __syncthreads();
        sh[t] += u;
        __syncthreads();
    }
    if (t < NBLK) HT[(size_t)t * HSTR + kb] = sh[t] - v;   // exclusive
    if (t == 255) tot[kb] = sh[255];
}

// pass C: 512 threads, 8 edges/thread; rank per (block,bucket) via LDS atomics,
// LDS-sort by bucket, write bucket-sorted runs. Computes bbase in-LDS from tot;
// block 0 publishes it.
__global__ void kC_scatter(const int* __restrict__ src, const int* __restrict__ dst,
                           const unsigned* __restrict__ HT, const unsigned* __restrict__ tot,
                           unsigned* __restrict__ bbase, unsigned* __restrict__ pck) {
    __shared__ unsigned sCnt[NBKT];
    __shared__ unsigned sPos[NBKT];
    __shared__ unsigned sBB[NBKT];
    __shared__ unsigned sDelta[NBKT];
    __shared__ unsigned sBuf[EPB];
    __shared__ unsigned short sBkt[EPB];
    __shared__ unsigned sh[512];
    int tid = threadIdx.x;
    for (int k = tid; k < NBKT; k += 512) sCnt[k] = 0u;
    __syncthreads();
    int vcnt = NE - blockIdx.x * EPB;
    if (vcnt > EPB) vcnt = EPB;
    int e0 = blockIdx.x * EPB + tid * 8;
    int nv = vcnt - tid * 8;                // valid edges for this thread (of 8)
    int cnt8 = (nv >= 8) ? 8 : ((nv > 0) ? nv : 0);
    unsigned wE[8], bE[8], rE[8];
    if (nv >= 8) {
        int4 sa = *(const int4*)(src + e0);
        int4 sb = *(const int4*)(src + e0 + 4);
        int4 da = *(const int4*)(dst + e0);
        int4 db = *(const int4*)(dst + e0 + 4);
        int ss[8] = {sa.x, sa.y, sa.z, sa.w, sb.x, sb.y, sb.z, sb.w};
        int dd[8] = {da.x, da.y, da.z, da.w, db.x, db.y, db.z, db.w};
#pragma unroll
        for (int q = 0; q < 8; ++q) {
            unsigned d = (unsigned)dd[q];
            bE[q] = d >> 8;
            rE[q] = atomicAdd(&sCnt[bE[q]], 1u);
            wE[q] = (unsigned)ss[q] | ((d & 255u) << 17);
        }
    } else if (cnt8 > 0) {
#pragma unroll
        for (int q = 0; q < 8; ++q) {
            if (q < cnt8) {
                unsigned d = (unsigned)dst[e0 + q];
                bE[q] = d >> 8;
                rE[q] = atomicAdd(&sCnt[bE[q]], 1u);
                wE[q] = (unsigned)src[e0 + q] | ((d & 255u) << 17);
            }
        }
    }
    __syncthreads();
    // scan 1: sCnt -> sPos (exclusive within block; 1 entry/thread, 512-wide)
    {
        unsigned v = (tid < NBKT) ? sCnt[tid] : 0u;
        sh[tid] = v;
        __syncthreads();
        for (int off = 1; off < 512; off <<= 1) {
            unsigned u = (tid >= off) ? sh[tid - off] : 0u;
            __syncthreads();
            sh[tid] += u;
            __syncthreads();
        }
        if (tid < NBKT) sPos[tid] = sh[tid] - v;
    }
    __syncthreads();
#pragma unroll
    for (int q = 0; q < 8; ++q) {
        if (q < cnt8) {
            unsigned i = sPos[bE[q]] + rE[q];
            sBuf[i] = wE[q];
            sBkt[i] = (unsigned short)bE[q];
        }
    }
    // scan 2: tot -> sBB (bucket bases)
    {
        unsigned v = (tid < NBKT) ? tot[tid] : 0u;
        sh[tid] = v;
        __syncthreads();
        for (int off = 1; off < 512; off <<= 1) {
            unsigned u = (tid >= off) ? sh[tid - off] : 0u;
            __syncthreads();
            sh[tid] += u;
            __syncthreads();
        }
        if (tid < NBKT) sBB[tid] = sh[tid] - v;
    }
    __syncthreads();
    if (blockIdx.x == 0) {
        for (int k = tid; k < NBKT; k += 512) bbase[k] = sBB[k];
        if (tid == 0) bbase[NBKT] = NE;
    }
    {
        const unsigned* row = HT + (size_t)blockIdx.x * HSTR;
        for (int k = tid; k < NBKT; k += 512)
            sDelta[k] = sBB[k] + row[k] - sPos[k];
    }
    __syncthreads();
    for (int i = tid; i < vcnt; i += 512)
        pck[i + sDelta[sBkt[i]]] = sBuf[i];
}

// kG1: 512 threads per bucket. LDS sort ONCE; export sorted bsrc + offsets so kG2
// can skip its sort. Then 2 threads/node consume interleaved halves; per-node MLP
// -> z2 row (fp16) + er2 on threads <256.
__global__ void kG1_node(const unsigned* __restrict__ bbase, const unsigned* __restrict__ pck,
                         const float4* __restrict__ pfeat, const float* __restrict__ er1,
                         const float* __restrict__ W1, const float* __restrict__ b1,
                         const float* __restrict__ W2, const float* __restrict__ al2,
                         const float* __restrict__ ar2,
                         __half* __restrict__ z2h, float* __restrict__ er2,
                         unsigned* __restrict__ bsrc, unsigned* __restrict__ offsets) {
    __shared__ float sW1[192], sb1[64], sW2[1920], sal2[30], sar2[30];
    __shared__ unsigned h[256], pr[256], cur[256];
    __shared__ unsigned sBuf[SCAP];
    __shared__ float xch[4][256];
    int tid = threadIdx.x;
    for (int i = tid; i < 192; i += 512) sW1[i] = W1[(i >> 6)*128 + (i & 63)];
    for (int i = tid; i < 1920; i += 512) sW2[i] = W2[(i / 30)*60 + (i % 30)];
    if (tid < 64) sb1[tid] = b1[tid];
    if (tid < 30) { sal2[tid] = al2[tid]; sar2[tid] = ar2[tid]; }
    unsigned bb = bbase[blockIdx.x], be = bbase[blockIdx.x + 1];
    unsigned cnt = be - bb;
    bool fit = (cnt <= SCAP);               // block-uniform
    if (tid < 256) { h[tid] = 0u; cur[tid] = 0u; }
    __syncthreads();
    if (fit) {
        for (unsigned i = bb + tid; i < be; i += 512) atomicAdd(&h[pck[i] >> 17], 1u);
        __syncthreads();
        unsigned v = 0;
        if (tid < 256) { v = h[tid]; pr[tid] = v; }
        __syncthreads();
        for (int off = 1; off < 256; off <<= 1) {
            unsigned u = 0;
            if (tid < 256 && tid >= off) u = pr[tid - off];
            __syncthreads();
            if (tid < 256) pr[tid] += u;
            __syncthreads();
        }
        if (tid < 256) pr[tid] -= v;
        __syncthreads();
        for (unsigned i = bb + tid; i < be; i += 512) {
            unsigned w = pck[i];
            unsigned j = w >> 17;
            unsigned r = atomicAdd(&cur[j], 1u);
            sBuf[pr[j] + r] = w & 0x1FFFFu;
        }
        __syncthreads();
        // export: sorted src list (coalesced) + per-node offsets for kG2
        for (unsigned i = tid; i < cnt; i += 512) bsrc[bb + i] = sBuf[i];
        if (tid < 256) {
            int node = blockIdx.x * 256 + tid;
            if (node < NN) offsets[node] = bb + pr[tid];
            else if (node == NN) offsets[NN] = NE;
        }
        if (blockIdx.x == NBKT - 1 && tid == 160) offsets[NN] = NE;  // node==NN slot
    }
    int j = tid & 255, half = tid >> 8;
    int n = blockIdx.x * 256 + j;
    bool valid = (n < NN);
    float s0 = 0.f, s1 = 0.f, s2 = 0.f, sp = 0.f;
    if (valid) {
        float erd = er1[n];
        if (fit) {
            unsigned beg = pr[j], end = beg + h[j];
            unsigned i = beg + half;                 // this half's edges: stride 2
            for (; i + 2 < end; i += 4) {            // 2 gathers in flight
                unsigned sA = sBuf[i], sB = sBuf[i + 2];
                float4 vA = pfeat[sA], vB = pfeat[sB];
                float eA = vA.w + erd; eA = (eA >= 0.f) ? eA : 0.2f*eA; float pA = __expf(eA);
                s0 += pA*vA.x; s1 += pA*vA.y; s2 += pA*vA.z; sp += pA;
                float eB = vB.w + erd; eB = (eB >= 0.f) ? eB : 0.2f*eB; float pB = __expf(eB);
                s0 += pB*vB.x; s1 += pB*vB.y; s2 += pB*vB.z; sp += pB;
            }
            if (i < end) {
                unsigned s = sBuf[i];
                float4 v = pfeat[s];
                float ee = v.w + erd; ee = (ee >= 0.f) ? ee : 0.2f*ee; float p = __expf(ee);
                s0 += p*v.x; s1 += p*v.y; s2 += p*v.z; sp += p;
            }
        } else if (half == 0) {                      // exact fallback (never here)
            for (unsigned i = bb; i < be; ++i) {
                unsigned w = pck[i];
                if ((int)(w >> 17) == j) {
                    float4 v = pfeat[w & 0x1FFFFu];
                    float ee = v.w + erd; ee = (ee >= 0.f) ? ee : 0.2f*ee; float p = __expf(ee);
                    s0 += p*v.x; s1 += p*v.y; s2 += p*v.z; sp += p;
                }
            }
        }
    }
    if (half == 1) { xch[0][j] = s0; xch[1][j] = s1; xch[2][j] = s2; xch[3][j] = sp; }
    __syncthreads();
    if (tid >= 256 || !valid) return;
    s0 += xch[0][tid]; s1 += xch[1][tid]; s2 += xch[2][tid]; sp += xch[3][tid];
    float inv = (sp > 0.f) ? 1.f / sp : 0.f;
    float ax = s0 * inv, ay = s1 * inv, az = s2 * inv;
    float z[30];
#pragma unroll
    for (int c = 0; c < 30; ++c) z[c] = 0.f;
    for (int jj = 0; jj < 64; ++jj) {
        float rj = fmaxf(ax*sW1[jj] + ay*sW1[64 + jj] + az*sW1[128 + jj] + sb1[jj], 0.f);
#pragma unroll
        for (int c = 0; c < 30; ++c) z[c] += rj * sW2[jj*30 + c];
    }
    float sl = 0.f, sr = 0.f;
#pragma unroll
    for (int c = 0; c < 30; ++c) { sl += z[c] * sal2[c]; sr += z[c] * sar2[c]; }
    float4* outp = (float4*)(z2h + (size_t)n * 32);
    outp[0] = make_float4(PK2(z[0],z[1]),  PK2(z[2],z[3]),  PK2(z[4],z[5]),  PK2(z[6],z[7]));
    outp[1] = make_float4(PK2(z[8],z[9]),  PK2(z[10],z[11]),PK2(z[12],z[13]),PK2(z[14],z[15]));
    outp[2] = make_float4(PK2(z[16],z[17]),PK2(z[18],z[19]),PK2(z[20],z[21]),PK2(z[22],z[23]));
    outp[3] = make_float4(PK2(z[24],z[25]),PK2(z[26],z[27]),PK2(z[28],z[29]),PK2(sl, 0.f));
    er2[n] = sr;
}

// kG2: 512 threads per bucket. NO sort — stage pre-sorted bsrc into LDS (coalesced),
// consume with offsets; 2 threads/node interleaved halves; block reduce -> partials.
__global__ void kG2_layer2(const unsigned* __restrict__ bbase, const unsigned* __restrict__ pck,
                           const unsigned* __restrict__ bsrc, const unsigned* __restrict__ offsets,
                           const __half* __restrict__ z2h, const float* __restrict__ er2,
                           float* __restrict__ part) {
    __shared__ unsigned sBuf[SCAP];
    __shared__ float xsp[2][256];
    __shared__ float shr[8][32];
    int tid = threadIdx.x;
    int lane = tid & 63, wv = tid >> 6;   // 8 waves
    unsigned bb = bbase[blockIdx.x], be = bbase[blockIdx.x + 1];
    unsigned cnt = be - bb;
    bool fit = (cnt <= SCAP);
    if (fit) {
        for (unsigned i = tid; i < cnt; i += 512) sBuf[i] = bsrc[bb + i];
        __syncthreads();
    }
    int j = tid & 255, half = tid >> 8;
    int n = blockIdx.x * 256 + j;
    bool valid = (n < NN);
    float acc[30];
#pragma unroll
    for (int q = 0; q < 30; ++q) acc[q] = 0.f;
    float sp = 0.f;
    if (valid) {
        float erd = er2[n];
#define PROC(r0, r1, r2, r3) { \
            float el = __half2float(__low2half(__builtin_bit_cast(__half2, (r3).w))); \
            float ee = el + erd; \
            ee = (ee >= 0.f) ? ee : 0.2f * ee; \
            float p = __expf(ee); \
            sp += p; \
            float2 f; \
            f = __half22float2(__builtin_bit_cast(__half2, (r0).x)); acc[0]  += p*f.x; acc[1]  += p*f.y; \
            f = __half22float2(__builtin_bit_cast(__half2, (r0).y)); acc[2]  += p*f.x; acc[3]  += p*f.y; \
            f = __half22float2(__builtin_bit_cast(__half2, (r0).z)); acc[4]  += p*f.x; acc[5]  += p*f.y; \
            f = __half22float2(__builtin_bit_cast(__half2, (r0).w)); acc[6]  += p*f.x; acc[7]  += p*f.y; \
            f = __half22float2(__builtin_bit_cast(__half2, (r1).x)); acc[8]  += p*f.x; acc[9]  += p*f.y; \
            f = __half22float2(__builtin_bit_cast(__half2, (r1).y)); acc[10] += p*f.x; acc[11] += p*f.y; \
            f = __half22float2(__builtin_bit_cast(__half2, (r1).z)); acc[12] += p*f.x; acc[13] += p*f.y; \
            f = __half22float2(__builtin_bit_cast(__half2, (r1).w)); acc[14] += p*f.x; acc[15] += p*f.y; \
            f = __half22float2(__builtin_bit_cast(__half2, (r2).x)); acc[16] += p*f.x; acc[17] += p*f.y; \
            f = __half22float2(__builtin_bit_cast(__half2, (r2).y)); acc[18] += p*f.x; acc[19] += p*f.y; \
            f = __half22float2(__builtin_bit_cast(__half2, (r2).z)); acc[20] += p*f.x; acc[21] += p*f.y; \
            f = __half22float2(__builtin_bit_cast(__half2, (r2).w)); acc[22] += p*f.x; acc[23] += p*f.y; \
            f = __half22float2(__builtin_bit_cast(__half2, (r3).x)); acc[24] += p*f.x; acc[25] += p*f.y; \
            f = __half22float2(__builtin_bit_cast(__half2, (r3).y)); acc[26] += p*f.x; acc[27] += p*f.y; \
            f = __half22float2(__builtin_bit_cast(__half2, (r3).z)); acc[28] += p*f.x; acc[29] += p*f.y; }
        if (fit) {
            unsigned beg = offsets[n] - bb;
            unsigned end = ((j == 255) ? be : offsets[n + 1]) - bb;
            unsigned i = beg + half;                 // this half's edges: stride 2
            for (; i + 2 < end; i += 4) {            // 2 rows in flight
                unsigned sA = sBuf[i], sB = sBuf[i + 2];
                const float4* zA = (const float4*)(z2h + (size_t)sA * 32);
                const float4* zB = (const float4*)(z2h + (size_t)sB * 32);
                float4 a0 = zA[0], a1 = zA[1], a2 = zA[2], a3 = zA[3];
                float4 b0 = zB[0], b1 = zB[1], b2 = zB[2], b3 = zB[3];
                PROC(a0, a1, a2, a3)
                PROC(b0, b1, b2, b3)
            }
            if (i < end) {
                unsigned s = sBuf[i];
                const float4* zr = (const float4*)(z2h + (size_t)s * 32);
                float4 r0 = zr[0], r1 = zr[1], r2 = zr[2], r3 = zr[3];
                PROC(r0, r1, r2, r3)
            }
        } else if (half == 0) {                      // exact fallback (never here)
            for (unsigned i = bb; i < be; ++i) {
                unsigned w = pck[i];
                if ((int)(w >> 17) == j) {
                    unsigned s = w & 0x1FFFFu;
                    const float4* zr = (const float4*)(z2h + (size_t)s * 32);
                    float4 r0 = zr[0], r1 = zr[1], r2 = zr[2], r3 = zr[3];
                    PROC(r0, r1, r2, r3)
                }
            }
        }
#undef PROC
    }
    xsp[half][j] = sp;
    __syncthreads();
    float spTot = xsp[0][j] + xsp[1][j];
    float inv = (spTot > 0.f) ? 1.f / spTot : 0.f;
#pragma unroll
    for (int q = 0; q < 30; ++q) acc[q] *= inv;
#pragma unroll
    for (int q = 0; q < 30; ++q)
        for (int off = 32; off > 0; off >>= 1) acc[q] += __shfl_down(acc[q], off);
    if (lane == 0) {
#pragma unroll
        for (int q = 0; q < 30; ++q) shr[wv][q] = acc[q];
    }
    __syncthreads();
    if (tid < 30) {
        float s = 0.f;
#pragma unroll
        for (int w8 = 0; w8 < 8; ++w8) s += shr[w8][tid];
        part[blockIdx.x * 32 + tid] = s;
    }
}

// single block: image path, sum partials, a00 = colsum/N + b2, concat, log_softmax
__global__ void k6_final(const float* __restrict__ x, const float* __restrict__ vocab,
                         const float* __restrict__ W_lin1, const float* __restrict__ w2,
                         const float* __restrict__ w3, const float* __restrict__ W4,
                         const float* __restrict__ b2, const float* __restrict__ part,
                         float* __restrict__ out) {
    __shared__ float sh[256];
    __shared__ float hvec[70];
    int tid = threadIdx.x;
    int r = tid >> 3, sub = tid & 7;
    float pt = 0.f;
    if (r < 30) {
        for (int k = sub; k < 512; k += 8) pt += W_lin1[r*512 + k] * x[k];
    }
    sh[tid] = pt;
    __syncthreads();
    if (tid < 30) {
        float hi = 0.f;
        for (int i = 0; i < 8; ++i) hi += sh[tid*8 + i];
        float acc = 0.f;
        for (int k = 0; k < 64; ++k) acc += w3[k] / (1.f + __expf(-w2[k] * hi));
        hvec[30 + tid] = 1.f / (1.f + __expf(-acc));
        float cs = 0.f;
        for (int b = 0; b < NBKT; ++b) cs += part[b*32 + tid];
        hvec[tid] = cs * (1.0f / (float)NN) + b2[tid];
    }
    if (tid >= 64 && tid < 74) hvec[60 + (tid - 64)] = vocab[tid - 64];
    __syncthreads();
    if (tid == 0) {
        float p0 = 0.f, p1 = 0.f;
        for (int k = 0; k < 70; ++k) {
            p0 += W4[k] * hvec[k];
            p1 += W4[70 + k] * hvec[k];
        }
        float mx = fmaxf(p0, p1);
        float l = logf(__expf(p0 - mx) + __expf(p1 - mx));
        out[0] = p0 - mx - l;
        out[1] = p1 - mx - l;
    }
}

extern "C" void kernel_launch(void* const* d_in, const int* in_sizes, int n_in,
                              void* d_out, int out_size, void* d_ws, size_t ws_size,
                              hipStream_t stream) {
    const float* x      = (const float*)d_in[0];
    const float* feat   = (const float*)d_in[1];
    const float* vocab  = (const float*)d_in[2];
    const int*   src    = (const int*)d_in[3];
    const int*   dst    = (const int*)d_in[4];
    const float* W_lin1 = (const float*)d_in[5];
    const float* w_c2   = (const float*)d_in[6];
    const float* w_c3   = (const float*)d_in[7];
    const float* W_lin4 = (const float*)d_in[8];
    const float* W1     = (const float*)d_in[9];
    const float* al1    = (const float*)d_in[10];
    const float* ar1    = (const float*)d_in[11];
    const float* b1     = (const float*)d_in[12];
    const float* W2     = (const float*)d_in[13];
    const float* al2    = (const float*)d_in[14];
    const float* ar2    = (const float*)d_in[15];
    const float* b2     = (const float*)d_in[16];
    float* out = (float*)d_out;
    float* w = (float*)d_ws;

    float4*   pfeat   = (float4*)(w + OFF_PFEAT);
    float*    er1     = w + OFF_ER1;
    float*    er2     = w + OFF_ER2;
    unsigned* tot     = (unsigned*)(w + OFF_TOT);
    unsigned* bbase   = (unsigned*)(w + OFF_BBASE);
    unsigned* HT      = (unsigned*)(w + OFF_HT);
    unsigned* pck     = (unsigned*)(w + OFF_PCK);
    unsigned* offsets = (unsigned*)(w + OFF_OFFS);
    unsigned* bsrc    = (unsigned*)(w + OFF_BSRC);
    __half*   z2h     = (__half*)(w + OFF_Z2H);
    float*    part    = w + OFF_PARTS;

    kA_hist<<<NBLK, 512, 0, stream>>>(dst, feat, W1, al1, ar1, HT, pfeat, er1);
    kB_scan<<<NBKT, 256, 0, stream>>>(HT, tot);
    kC_scatter<<<NBLK, 512, 0, stream>>>(src, dst, HT, tot, bbase, pck);
    kG1_node<<<NBKT, 512, 0, stream>>>(bbase, pck, pfeat, er1, W1, b1, W2, al2, ar2,
                                       z2h, er2, bsrc, offsets);
    kG2_layer2<<<NBKT, 512, 0, stream>>>(bbase, pck, bsrc, offsets, z2h, er2, part);
    k6_final<<<1, 256, 0, stream>>>(x, vocab, W_lin1, w_c2, w_c3, W_lin4, b2, part, out);
}